// Round 7
// baseline (264.932 us; speedup 1.0000x reference)
//
#include <hip/hip_runtime.h>

typedef __attribute__((ext_vector_type(8))) short short8;
typedef __attribute__((ext_vector_type(4))) float f32x4;
typedef __attribute__((ext_vector_type(16))) float f32x16;
typedef __attribute__((ext_vector_type(4))) int i32x4;

__device__ __forceinline__ unsigned short f2bf(float f){
  union { float f; unsigned int u; } cv; cv.f = f;
  unsigned int u = cv.u;
  u = (u + 0x7fffu + ((u >> 16) & 1u)) >> 16;
  return (unsigned short)u;
}
__device__ __forceinline__ float bf2f(unsigned short h){
  union { unsigned int u; float f; } cv; cv.u = ((unsigned int)h) << 16;
  return cv.f;
}

typedef unsigned int u32g __attribute__((address_space(1)));
typedef unsigned int u32l __attribute__((address_space(3)));
__device__ __forceinline__ void gload16(const void* g, void* l){
  __builtin_amdgcn_global_load_lds((const u32g*)g, (u32l*)l, 16, 0, 0);
}

__device__ __forceinline__ unsigned int cvtpk_bf16(float lo, float hi){
  unsigned int r;
  asm("v_cvt_pk_bf16_f32 %0, %1, %2" : "=v"(r) : "v"(lo), "v"(hi));
  return r;
}

#define BARRIER() asm volatile("s_barrier" ::: "memory")
#define WAITV0()  asm volatile("s_waitcnt vmcnt(0)" ::: "memory")
#define WAITLGKM0() asm volatile("s_waitcnt lgkmcnt(0)" ::: "memory")

// ---------------- reduction: per-batch mean / rstd ----------------
__global__ __launch_bounds__(256) void reduce_partial_k(const float* __restrict__ x,
                                                        float2* __restrict__ partial){
  const int b = blockIdx.y, blk = blockIdx.x;
  const float4* xp = (const float4*)(x + (size_t)b*1048576 + (size_t)blk*16384);
  float s = 0.f, sq = 0.f;
  #pragma unroll
  for (int i = 0; i < 16; ++i){
    float4 v = xp[threadIdx.x + i*256];
    s  += v.x + v.y + v.z + v.w;
    sq += v.x*v.x + v.y*v.y + v.z*v.z + v.w*v.w;
  }
  #pragma unroll
  for (int m = 1; m < 64; m <<= 1){ s += __shfl_xor(s, m); sq += __shfl_xor(sq, m); }
  __shared__ float2 acc[4];
  if ((threadIdx.x & 63) == 0) acc[threadIdx.x >> 6] = make_float2(s, sq);
  __syncthreads();
  if (threadIdx.x == 0){
    float S = 0.f, Q = 0.f;
    for (int i = 0; i < 4; ++i){ S += acc[i].x; Q += acc[i].y; }
    partial[b*64 + blk] = make_float2(S, Q);
  }
}

__global__ __launch_bounds__(256) void reduce_final_k(const float2* __restrict__ partial,
                                                      float2* __restrict__ stats){
  const int w = threadIdx.x >> 6, lane = threadIdx.x & 63;
  float2 p = partial[w*64 + lane];
  float s = p.x, q = p.y;
  #pragma unroll
  for (int m = 1; m < 64; m <<= 1){ s += __shfl_xor(s, m); q += __shfl_xor(q, m); }
  if (lane == 0){
    const float inv = 1.0f/1048576.0f;
    float mean = s*inv;
    float var  = q*inv - mean*mean;
    stats[w] = make_float2(mean, rsqrtf(var + 1e-6f));
  }
}

// ---------------- weight conversion (fold scale*log2e into Q) ----------------
__global__ __launch_bounds__(256) void convert_w_k(const float* __restrict__ qkv_w,
                                                   const float* __restrict__ qkv_b,
                                                   const float* __restrict__ proj_w,
                                                   unsigned short* __restrict__ Wqk,
                                                   unsigned short* __restrict__ Wv,
                                                   unsigned short* __restrict__ Wp,
                                                   float* __restrict__ bias_qk){
  const float SQ = 0.0625f * 1.44269504088896340736f; // (C^-0.5) * log2(e)
  int id = blockIdx.x * 256 + threadIdx.x;
  if (id < 131072){                       // q,k rows (o < 512)
    int o = id >> 8;
    float sc = (o < 256) ? SQ : 1.0f;
    Wqk[id] = f2bf(qkv_w[id] * sc);
    if (id < 512) bias_qk[id] = qkv_b[id] * ((id < 256) ? SQ : 1.0f);
  } else if (id < 196608){                // v rows (o in [512,768))
    Wv[id - 131072] = f2bf(qkv_w[id]);
  } else {                                // proj
    int j = id - 196608;
    Wp[j] = f2bf(proj_w[j]);
  }
}

// ---------------- GroupNorm + transpose: x[b][c][n] -> xn_t[b][n][c] bf16 ----------------
__global__ __launch_bounds__(256) void norm_transpose_k(const float* __restrict__ x,
                                                        const float* __restrict__ gamma,
                                                        const float* __restrict__ beta,
                                                        const float2* __restrict__ stats,
                                                        unsigned short* __restrict__ xnt){
  __shared__ float tile[64][65];
  const int b = blockIdx.z, n0 = blockIdx.x*64, c0 = blockIdx.y*64;
  const float2 st = stats[b];
  const int t = threadIdx.x;
  const int col = t & 63, rb = t >> 6;
  #pragma unroll
  for (int i = 0; i < 16; ++i){
    int rr = i*4 + rb;
    float xv = x[((size_t)b*256 + c0 + rr)*4096 + n0 + col];
    tile[rr][col] = (xv - st.x) * st.y * gamma[c0+rr] + beta[c0+rr];
  }
  __syncthreads();
  #pragma unroll
  for (int i = 0; i < 16; ++i){
    int nr = i*4 + rb;
    xnt[((size_t)b*4096 + n0 + nr)*256 + c0 + col] = f2bf(tile[col][nr]);
  }
}

// ---------------- NT GEMM: C[m][n] = sum_k A[m][k]*B[n][k], K=256 ----------------
// vtile!=0: bf16 output stored as [n/16][m/32][32][16] tiles (for direct MFMA A-frag loads)
__global__ __launch_bounds__(256) void gemm_nt_k(const unsigned short* __restrict__ A,
                                                 const unsigned short* __restrict__ B,
                                                 int lda, int ldb, long sA, long sB,
                                                 const float* __restrict__ bias_m,
                                                 const float* __restrict__ bias_n,
                                                 const float* __restrict__ resid, long sR,
                                                 float* __restrict__ outF,
                                                 unsigned short* __restrict__ outB,
                                                 int ldc, long sC, int vtile){
  __shared__ unsigned short As[64][40];
  __shared__ unsigned short Bs[64][40];
  const int b  = blockIdx.z;
  const int m0 = blockIdx.x * 64, n0 = blockIdx.y * 64;
  const unsigned short* Ab = A + (size_t)b * sA;
  const unsigned short* Bb = B + (size_t)b * sB;
  const int t = threadIdx.x;
  const int lane = t & 63, w = t >> 6;
  const int g = lane >> 4, r = lane & 15;
  const int wm = (w >> 1) * 32, wn = (w & 1) * 32;
  const int lrow = t >> 2, lcol = (t & 3) * 8;
  f32x4 acc00 = {0,0,0,0}, acc01 = {0,0,0,0}, acc10 = {0,0,0,0}, acc11 = {0,0,0,0};
  for (int ks = 0; ks < 8; ++ks){
    short8 av = *(const short8*)(Ab + (size_t)(m0 + lrow) * lda + ks*32 + lcol);
    short8 bv = *(const short8*)(Bb + (size_t)(n0 + lrow) * ldb + ks*32 + lcol);
    __syncthreads();
    *(short8*)&As[lrow][lcol] = av;
    *(short8*)&Bs[lrow][lcol] = bv;
    __syncthreads();
    short8 af0 = *(const short8*)&As[wm + r][g*8];
    short8 af1 = *(const short8*)&As[wm + 16 + r][g*8];
    short8 bf0 = *(const short8*)&Bs[wn + r][g*8];
    short8 bf1 = *(const short8*)&Bs[wn + 16 + r][g*8];
    acc00 = __builtin_amdgcn_mfma_f32_16x16x32_bf16(af0, bf0, acc00, 0, 0, 0);
    acc01 = __builtin_amdgcn_mfma_f32_16x16x32_bf16(af0, bf1, acc01, 0, 0, 0);
    acc10 = __builtin_amdgcn_mfma_f32_16x16x32_bf16(af1, bf0, acc10, 0, 0, 0);
    acc11 = __builtin_amdgcn_mfma_f32_16x16x32_bf16(af1, bf1, acc11, 0, 0, 0);
  }
  f32x4 accs[2][2] = {{acc00, acc01},{acc10, acc11}};
  #pragma unroll
  for (int mi = 0; mi < 2; ++mi)
    #pragma unroll
    for (int ni = 0; ni < 2; ++ni)
      #pragma unroll
      for (int j = 0; j < 4; ++j){
        int gm = m0 + wm + mi*16 + g*4 + j;
        int gn = n0 + wn + ni*16 + r;
        float vv = accs[mi][ni][j];
        if (bias_m) vv += bias_m[gm];
        if (bias_n) vv += bias_n[gn];
        if (resid)  vv += resid[(size_t)b*sR + (size_t)gm*ldc + gn];
        if (outB){
          size_t off;
          if (vtile)
            off = (size_t)b*sC + (size_t)(gn >> 4)*4096 + (gm >> 5)*512 + (gm & 31)*16 + (gn & 15);
          else
            off = (size_t)b*sC + (size_t)gm*ldc + gn;
          outB[off] = f2bf(vv);
        } else {
          outF[(size_t)b*sC + (size_t)gm*ldc + gn] = vv;
        }
      }
}

// ---------------- flash attention: 8 waves = 2 qg x 4 cg, 64 q-rows/wave, KVBLK=128 ----------------
// q,k in qk[b][n][512]; V pre-tiled vt[b][k/16][c/32][32][16] (direct L2->reg A-frags).
// Fixed-M softmax p = exp2(S-24). P exchanged via LDS (32KB). K staged via dbuf (2x64KB).
__global__ __launch_bounds__(512, 1) void attn_k(const unsigned short* __restrict__ qk,
                                                 const unsigned short* __restrict__ vt,
                                                 unsigned short* __restrict__ po,
                                                 float* __restrict__ ml){
  __shared__ __align__(16) char smem[163840];  // K dbuf 2x65536 | P 32768
  const int id = blockIdx.x;
  const int combo = id & 7, qb = id >> 3;      // combo -> XCD (L2 shares K/V per combo)
  const int b = combo >> 1, ks = combo & 1;
  const int q0 = qb * 128;
  const int t = threadIdx.x, lane = t & 63, w = t >> 6;
  const int qg = w & 1, cg = w >> 1;
  const int hi = lane >> 5, l31 = lane & 31;
  const unsigned short* qkb = qk + (size_t)b * 4096 * 512;
  const unsigned short* vtb = vt + (size_t)b * 1048576;
  char* Kb0 = smem;
  char* Kb1 = smem + 65536;
  char* Pb  = smem + 131072;

  // ---- prologue: stage this block's 128 Q rows through LDS, read fragments ----
  #pragma unroll
  for (int ii = 0; ii < 8; ++ii){
    int row = w*16 + 2*ii + hi;
    const unsigned short* src = qkb + (size_t)(q0 + row)*512
                              + (((l31*16) ^ ((row & 15) << 4)) >> 1);
    gload16(src, Kb0 + (w*16 + 2*ii)*512);
  }
  WAITV0(); BARRIER();
  short8 qf[2][16];
  #pragma unroll
  for (int qt = 0; qt < 2; ++qt){
    int row = qg*64 + qt*32 + l31;
    const char* rp = Kb0 + row*512;
    int sw = (row & 15) << 4;
    #pragma unroll
    for (int s = 0; s < 16; ++s)
      qf[qt][s] = *(const short8*)(rp + ((s*32 + hi*16) ^ sw));
  }
  WAITLGKM0(); BARRIER();   // all Q reads done before K staging overwrites

  f32x16 O[2][2];
  #pragma unroll
  for (int qt = 0; qt < 2; ++qt)
    #pragma unroll
    for (int cb = 0; cb < 2; ++cb)
      #pragma unroll
      for (int jj = 0; jj < 16; ++jj) O[qt][cb][jj] = 0.f;
  float l0 = 0.f, l1 = 0.f;
  const int kswz = (l31 & 15) << 4;

  // stage K tile kt (128 rows x 512B) into its dbuf half
  auto stageK = [&](int kt){
    const int kbase = ks*2048 + kt*128;
    char* dst = (kt & 1) ? Kb1 : Kb0;
    #pragma unroll
    for (int ii = 0; ii < 8; ++ii){
      int row = w*16 + 2*ii + hi;
      const unsigned short* src = qkb + (size_t)(kbase + row)*512 + 256
                                + (((l31*16) ^ ((row & 15) << 4)) >> 1);
      gload16(src, dst + (w*16 + 2*ii)*512);
    }
  };
  stageK(0);

  const char* Pq0 = Pb + (qg*2 + 0)*8192 + lane*16;
  const char* Pq1 = Pb + (qg*2 + 1)*8192 + lane*16;

  for (int kt = 0; kt < 16; ++kt){
    const char* Kt = (kt & 1) ? Kb1 : Kb0;
    const int kbase = ks*2048 + kt*128;

    WAITV0();    // own K stage of tile kt landed (issued an iteration ago)
    BARRIER();   // (A) tile kt staged by all; prev P reads done

    if (kt < 15) stageK(kt + 1);

    // ---- S^T = K[32k of cg] . Q : 16 c-steps, each K frag feeds both q-tiles ----
    f32x16 S0, S1;
    #pragma unroll
    for (int jj = 0; jj < 16; ++jj){ S0[jj] = 0.f; S1[jj] = 0.f; }
    const char* krow = Kt + (cg*32 + l31)*512;
    __builtin_amdgcn_s_setprio(1);
    #pragma unroll
    for (int s = 0; s < 16; ++s){
      short8 kf = *(const short8*)(krow + ((s*32 + hi*16) ^ kswz));
      S0 = __builtin_amdgcn_mfma_f32_32x32x16_bf16(kf, qf[0][s], S0, 0, 0, 0);
      S1 = __builtin_amdgcn_mfma_f32_32x32x16_bf16(kf, qf[1][s], S1, 0, 0, 0);
    }
    __builtin_amdgcn_s_setprio(0);

    // ---- fixed-M softmax + pack + P-write, q-tile 0 ----
    {
      float p[16];
      #pragma unroll
      for (int jj = 0; jj < 16; ++jj) p[jj] = exp2f(S0[jj] - 24.0f);
      l0 += ((p[0]+p[1]) + (p[2]+p[3])) + ((p[4]+p[5]) + (p[6]+p[7]))
          + ((p[8]+p[9]) + (p[10]+p[11])) + ((p[12]+p[13]) + (p[14]+p[15]));
      unsigned int a0 = cvtpk_bf16(p[0],p[1]),   a1 = cvtpk_bf16(p[2],p[3]);
      unsigned int a2 = cvtpk_bf16(p[4],p[5]),   a3 = cvtpk_bf16(p[6],p[7]);
      unsigned int a4 = cvtpk_bf16(p[8],p[9]),   a5 = cvtpk_bf16(p[10],p[11]);
      unsigned int a6 = cvtpk_bf16(p[12],p[13]), a7 = cvtpk_bf16(p[14],p[15]);
      asm("v_permlane32_swap_b32 %0, %1" : "+v"(a0), "+v"(a2));
      asm("v_permlane32_swap_b32 %0, %1" : "+v"(a1), "+v"(a3));
      asm("v_permlane32_swap_b32 %0, %1" : "+v"(a4), "+v"(a6));
      asm("v_permlane32_swap_b32 %0, %1" : "+v"(a5), "+v"(a7));
      i32x4 w0 = {(int)a0,(int)a1,(int)a2,(int)a3};
      i32x4 w1 = {(int)a4,(int)a5,(int)a6,(int)a7};
      *(short8*)(Pb + ((qg*2+0)*8 + cg*2    )*1024 + lane*16) = __builtin_bit_cast(short8, w0);
      *(short8*)(Pb + ((qg*2+0)*8 + cg*2 + 1)*1024 + lane*16) = __builtin_bit_cast(short8, w1);
    }
    // ---- q-tile 1 ----
    {
      float p[16];
      #pragma unroll
      for (int jj = 0; jj < 16; ++jj) p[jj] = exp2f(S1[jj] - 24.0f);
      l1 += ((p[0]+p[1]) + (p[2]+p[3])) + ((p[4]+p[5]) + (p[6]+p[7]))
          + ((p[8]+p[9]) + (p[10]+p[11])) + ((p[12]+p[13]) + (p[14]+p[15]));
      unsigned int a0 = cvtpk_bf16(p[0],p[1]),   a1 = cvtpk_bf16(p[2],p[3]);
      unsigned int a2 = cvtpk_bf16(p[4],p[5]),   a3 = cvtpk_bf16(p[6],p[7]);
      unsigned int a4 = cvtpk_bf16(p[8],p[9]),   a5 = cvtpk_bf16(p[10],p[11]);
      unsigned int a6 = cvtpk_bf16(p[12],p[13]), a7 = cvtpk_bf16(p[14],p[15]);
      asm("v_permlane32_swap_b32 %0, %1" : "+v"(a0), "+v"(a2));
      asm("v_permlane32_swap_b32 %0, %1" : "+v"(a1), "+v"(a3));
      asm("v_permlane32_swap_b32 %0, %1" : "+v"(a4), "+v"(a6));
      asm("v_permlane32_swap_b32 %0, %1" : "+v"(a5), "+v"(a7));
      i32x4 w0 = {(int)a0,(int)a1,(int)a2,(int)a3};
      i32x4 w1 = {(int)a4,(int)a5,(int)a6,(int)a7};
      *(short8*)(Pb + ((qg*2+1)*8 + cg*2    )*1024 + lane*16) = __builtin_bit_cast(short8, w0);
      *(short8*)(Pb + ((qg*2+1)*8 + cg*2 + 1)*1024 + lane*16) = __builtin_bit_cast(short8, w1);
    }

    // ---- V prefetch (direct L2 -> regs, tiled layout), first 4 k-slices ----
    short8 vp[8];
    #pragma unroll
    for (int sg = 0; sg < 4; ++sg){
      const unsigned short* vsrc = vtb + (size_t)((kbase >> 4) + sg)*4096 + l31*16 + hi*8;
      vp[2*sg]   = *(const short8*)(vsrc + (cg*2    )*512);
      vp[2*sg+1] = *(const short8*)(vsrc + (cg*2 + 1)*512);
    }

    WAITLGKM0();
    BARRIER();   // (B) all P fragments visible

    // ---- O += V.P^T : 8 k-slices x 2 c-blocks, V frag feeds both q-tiles ----
    __builtin_amdgcn_s_setprio(1);
    #pragma unroll
    for (int sg = 0; sg < 4; ++sg){
      short8 pf0 = *(const short8*)(Pq0 + sg*1024);
      short8 pf1 = *(const short8*)(Pq1 + sg*1024);
      O[0][0] = __builtin_amdgcn_mfma_f32_32x32x16_bf16(vp[2*sg],   pf0, O[0][0], 0, 0, 0);
      O[1][0] = __builtin_amdgcn_mfma_f32_32x32x16_bf16(vp[2*sg],   pf1, O[1][0], 0, 0, 0);
      O[0][1] = __builtin_amdgcn_mfma_f32_32x32x16_bf16(vp[2*sg+1], pf0, O[0][1], 0, 0, 0);
      O[1][1] = __builtin_amdgcn_mfma_f32_32x32x16_bf16(vp[2*sg+1], pf1, O[1][1], 0, 0, 0);
    }
    #pragma unroll
    for (int sg = 4; sg < 8; ++sg){
      const unsigned short* vsrc = vtb + (size_t)((kbase >> 4) + sg)*4096 + l31*16 + hi*8;
      short8 vf0 = *(const short8*)(vsrc + (cg*2    )*512);
      short8 vf1 = *(const short8*)(vsrc + (cg*2 + 1)*512);
      short8 pf0 = *(const short8*)(Pq0 + sg*1024);
      short8 pf1 = *(const short8*)(Pq1 + sg*1024);
      O[0][0] = __builtin_amdgcn_mfma_f32_32x32x16_bf16(vf0, pf0, O[0][0], 0, 0, 0);
      O[1][0] = __builtin_amdgcn_mfma_f32_32x32x16_bf16(vf0, pf1, O[1][0], 0, 0, 0);
      O[0][1] = __builtin_amdgcn_mfma_f32_32x32x16_bf16(vf1, pf0, O[0][1], 0, 0, 0);
      O[1][1] = __builtin_amdgcn_mfma_f32_32x32x16_bf16(vf1, pf1, O[1][1], 0, 0, 0);
    }
    __builtin_amdgcn_s_setprio(0);
  }

  // ---- epilogue: unnormalized partials + per-(cg) l partials ----
  float lf0 = l0 + __shfl_xor(l0, 32);
  float lf1 = l1 + __shfl_xor(l1, 32);
  unsigned short* pob = po + (size_t)combo * 1048576;   // [256 c][4096 q]
  #pragma unroll
  for (int qt = 0; qt < 2; ++qt)
    #pragma unroll
    for (int cb = 0; cb < 2; ++cb)
      #pragma unroll
      for (int jj = 0; jj < 16; ++jj){
        int c = cg*64 + cb*32 + (jj & 3) + 8*(jj >> 2) + 4*hi;
        int q = q0 + qg*64 + qt*32 + l31;
        pob[(size_t)c*4096 + q] = f2bf(O[qt][cb][jj]);
      }
  if (lane < 32){
    float* mlb = ml + (size_t)(combo*4 + cg)*4096 + q0 + qg*64;
    mlb[l31]      = lf0;
    mlb[32 + l31] = lf1;
  }
}

// ---------------- merge the 2 k-chunks (sum 8 l-partials): out ho[b][q][c] bf16 ----------------
__global__ __launch_bounds__(256) void attn_merge_k(const unsigned short* __restrict__ po,
                                                    const float* __restrict__ ml,
                                                    unsigned short* __restrict__ ho){
  __shared__ float Of[64][261];
  const int b = blockIdx.y, q0 = blockIdx.x * 64;
  const int t = threadIdx.x, ql = t & 63, ci = t >> 6;
  const int q = q0 + ql;
  float L = 0.f;
  #pragma unroll
  for (int ksv = 0; ksv < 2; ++ksv)
    #pragma unroll
    for (int cgv = 0; cgv < 4; ++cgv)
      L += ml[(size_t)((b*2 + ksv)*4 + cgv)*4096 + q];
  float inv = 1.0f / L;
  const unsigned short* p0 = po + (size_t)(b*2+0)*1048576 + q;
  const unsigned short* p1 = po + (size_t)(b*2+1)*1048576 + q;
  #pragma unroll
  for (int i = 0; i < 64; ++i){
    int c = ci + 4*i;
    float v = bf2f(p0[(size_t)c*4096]) + bf2f(p1[(size_t)c*4096]);
    Of[ql][c] = v * inv;
  }
  __syncthreads();
  const int qr = t >> 2, sub = t & 3;
  const float* rowp = Of[qr];
  unsigned short* dst = ho + ((size_t)(b*4096 + q0 + qr))*256;
  #pragma unroll
  for (int jj = 0; jj < 8; ++jj){
    int c = sub*8 + jj*32;
    float4 v0 = *(const float4*)(rowp + c);
    float4 v1 = *(const float4*)(rowp + c + 4);
    short8 o;
    o[0] = (short)f2bf(v0.x); o[1] = (short)f2bf(v0.y);
    o[2] = (short)f2bf(v0.z); o[3] = (short)f2bf(v0.w);
    o[4] = (short)f2bf(v1.x); o[5] = (short)f2bf(v1.y);
    o[6] = (short)f2bf(v1.z); o[7] = (short)f2bf(v1.w);
    *(short8*)(dst + c) = o;
  }
}

// ---------------- launch ----------------
extern "C" void kernel_launch(void* const* d_in, const int* in_sizes, int n_in,
                              void* d_out, int out_size, void* d_ws, size_t ws_size,
                              hipStream_t stream){
  const float* x      = (const float*)d_in[0];
  const float* gamma  = (const float*)d_in[1];
  const float* beta   = (const float*)d_in[2];
  const float* qkv_w  = (const float*)d_in[3];
  const float* qkv_b  = (const float*)d_in[4];
  const float* proj_w = (const float*)d_in[5];
  const float* proj_b = (const float*)d_in[6];
  float* out = (float*)d_out;
  char* ws = (char*)d_ws;

  float2* partial        = (float2*)(ws + 0);        // 2048 B
  float2* stats          = (float2*)(ws + 2048);     // 32 B
  float*  bias_qk        = (float*)(ws + 4096);      // 2048 B
  unsigned short* Wqk    = (unsigned short*)(ws + 8192);      // 512x256 bf16
  unsigned short* Wv     = (unsigned short*)(ws + 270336);    // 256x256
  unsigned short* Wp     = (unsigned short*)(ws + 401408);    // 256x256
  unsigned short* xnt    = (unsigned short*)(ws + 532480);    // 4x4096x256 bf16 (8.4 MB)
  unsigned short* qkbuf  = (unsigned short*)(ws + 8921088);   // 4x4096x512 bf16 (16.8 MB)
  unsigned short* vbuf   = (unsigned short*)(ws + 25698304);  // 4x(256x4096) bf16 tiled (8.4 MB)
  unsigned short* po     = (unsigned short*)(ws + 34086912);  // 8x256x4096 bf16 (16.8 MB)
  float*          ml     = (float*)(ws + 50864128);           // 8x4x4096 f32 (512 KB)
  unsigned short* ho     = xnt;  // xnt dead after QKV gemms -> reuse for attention output

  reduce_partial_k<<<dim3(64,4), 256, 0, stream>>>(x, partial);
  reduce_final_k<<<1, 256, 0, stream>>>(partial, stats);
  convert_w_k<<<1024, 256, 0, stream>>>(qkv_w, qkv_b, proj_w, Wqk, Wv, Wp, bias_qk);
  norm_transpose_k<<<dim3(64,4,4), 256, 0, stream>>>(x, gamma, beta, stats, xnt);
  // qk[b][n][o] = xn_t[b][n][:] . Wqk[o][:]   (M=4096, N=512)
  gemm_nt_k<<<dim3(64,8,4), 256, 0, stream>>>(xnt, Wqk, 256, 256, 4096L*256, 0,
      nullptr, bias_qk, nullptr, 0, nullptr, qkbuf, 512, 4096L*512, 0);
  // v tiled: vt[b][n/16][c/32][32][16] = Wv[o][:] . xn_t[b][n][:]
  gemm_nt_k<<<dim3(4,64,4), 256, 0, stream>>>(Wv, xnt, 256, 256, 0, 4096L*256,
      qkv_b + 512, nullptr, nullptr, 0, nullptr, vbuf, 4096, 256L*4096, 1);
  attn_k<<<dim3(256), 512, 0, stream>>>(qkbuf, vbuf, po, ml);
  attn_merge_k<<<dim3(64,4), 256, 0, stream>>>(po, ml, ho);
  // out[b][o][n] = Wp[o][:] . ho[b][n][:] + proj_b[o] + x[b][o][n]
  gemm_nt_k<<<dim3(4,64,4), 256, 0, stream>>>(Wp, ho, 256, 256, 0, 4096L*256,
      proj_b, nullptr, x, 1048576L, out, nullptr, 4096, 1048576L, 0);
}

// Round 8
// 186.430 us; speedup vs baseline: 1.4211x; 1.4211x over previous
//
#include <hip/hip_runtime.h>

typedef __attribute__((ext_vector_type(8))) short short8;
typedef __attribute__((ext_vector_type(4))) float f32x4;
typedef __attribute__((ext_vector_type(16))) float f32x16;
typedef __attribute__((ext_vector_type(4))) int i32x4;

__device__ __forceinline__ unsigned short f2bf(float f){
  union { float f; unsigned int u; } cv; cv.f = f;
  unsigned int u = cv.u;
  u = (u + 0x7fffu + ((u >> 16) & 1u)) >> 16;
  return (unsigned short)u;
}
__device__ __forceinline__ float bf2f(unsigned short h){
  union { unsigned int u; float f; } cv; cv.u = ((unsigned int)h) << 16;
  return cv.f;
}

typedef unsigned int u32g __attribute__((address_space(1)));
typedef unsigned int u32l __attribute__((address_space(3)));
__device__ __forceinline__ void gload16(const void* g, void* l){
  __builtin_amdgcn_global_load_lds((const u32g*)g, (u32l*)l, 16, 0, 0);
}

__device__ __forceinline__ unsigned int cvtpk_bf16(float lo, float hi){
  unsigned int r;
  asm("v_cvt_pk_bf16_f32 %0, %1, %2" : "=v"(r) : "v"(lo), "v"(hi));
  return r;
}
__device__ __forceinline__ unsigned int cvt2_fp8(float a, float b){
  unsigned int r;
  asm("v_cvt_pk_fp8_f32 %0, %1, %2" : "=v"(r) : "v"(a), "v"(b));
  return r;  // byte0 = fp8(a), byte1 = fp8(b)
}

#define BARRIER() asm volatile("s_barrier" ::: "memory")
#define WAITV0()  asm volatile("s_waitcnt vmcnt(0)" ::: "memory")
#define WAITLGKM0() asm volatile("s_waitcnt lgkmcnt(0)" ::: "memory")

// ---------------- reduction: per-batch mean / rstd ----------------
__global__ __launch_bounds__(256) void reduce_partial_k(const float* __restrict__ x,
                                                        float2* __restrict__ partial){
  const int b = blockIdx.y, blk = blockIdx.x;
  const float4* xp = (const float4*)(x + (size_t)b*1048576 + (size_t)blk*16384);
  float s = 0.f, sq = 0.f;
  #pragma unroll
  for (int i = 0; i < 16; ++i){
    float4 v = xp[threadIdx.x + i*256];
    s  += v.x + v.y + v.z + v.w;
    sq += v.x*v.x + v.y*v.y + v.z*v.z + v.w*v.w;
  }
  #pragma unroll
  for (int m = 1; m < 64; m <<= 1){ s += __shfl_xor(s, m); sq += __shfl_xor(sq, m); }
  __shared__ float2 acc[4];
  if ((threadIdx.x & 63) == 0) acc[threadIdx.x >> 6] = make_float2(s, sq);
  __syncthreads();
  if (threadIdx.x == 0){
    float S = 0.f, Q = 0.f;
    for (int i = 0; i < 4; ++i){ S += acc[i].x; Q += acc[i].y; }
    partial[b*64 + blk] = make_float2(S, Q);
  }
}

__global__ __launch_bounds__(256) void reduce_final_k(const float2* __restrict__ partial,
                                                      float2* __restrict__ stats){
  const int w = threadIdx.x >> 6, lane = threadIdx.x & 63;
  float2 p = partial[w*64 + lane];
  float s = p.x, q = p.y;
  #pragma unroll
  for (int m = 1; m < 64; m <<= 1){ s += __shfl_xor(s, m); q += __shfl_xor(q, m); }
  if (lane == 0){
    const float inv = 1.0f/1048576.0f;
    float mean = s*inv;
    float var  = q*inv - mean*mean;
    stats[w] = make_float2(mean, rsqrtf(var + 1e-6f));
  }
}

// ---------------- weight conversion (no pre-scaling; scale applied post-MFMA) ----------------
__global__ __launch_bounds__(256) void convert_w_k(const float* __restrict__ qkv_w,
                                                   const float* __restrict__ qkv_b,
                                                   const float* __restrict__ proj_w,
                                                   unsigned short* __restrict__ Wqk,
                                                   unsigned short* __restrict__ Wv,
                                                   unsigned short* __restrict__ Wp,
                                                   float* __restrict__ bias_qk){
  int id = blockIdx.x * 256 + threadIdx.x;
  if (id < 131072){                       // q,k rows (o < 512)
    Wqk[id] = f2bf(qkv_w[id]);
    if (id < 512) bias_qk[id] = qkv_b[id];
  } else if (id < 196608){                // v rows (o in [512,768))
    Wv[id - 131072] = f2bf(qkv_w[id]);
  } else {                                // proj
    int j = id - 196608;
    Wp[j] = f2bf(proj_w[j]);
  }
}

// ---------------- GroupNorm + transpose: x[b][c][n] -> xn_t[b][n][c] bf16 ----------------
__global__ __launch_bounds__(256) void norm_transpose_k(const float* __restrict__ x,
                                                        const float* __restrict__ gamma,
                                                        const float* __restrict__ beta,
                                                        const float2* __restrict__ stats,
                                                        unsigned short* __restrict__ xnt){
  __shared__ float tile[64][65];
  const int b = blockIdx.z, n0 = blockIdx.x*64, c0 = blockIdx.y*64;
  const float2 st = stats[b];
  const int t = threadIdx.x;
  const int col = t & 63, rb = t >> 6;
  #pragma unroll
  for (int i = 0; i < 16; ++i){
    int rr = i*4 + rb;
    float xv = x[((size_t)b*256 + c0 + rr)*4096 + n0 + col];
    tile[rr][col] = (xv - st.x) * st.y * gamma[c0+rr] + beta[c0+rr];
  }
  __syncthreads();
  #pragma unroll
  for (int i = 0; i < 16; ++i){
    int nr = i*4 + rb;
    xnt[((size_t)b*4096 + n0 + nr)*256 + c0 + col] = f2bf(tile[col][nr]);
  }
}

// ---------------- NT GEMM: C[m][n] = sum_k A[m][k]*B[n][k], K=256 ----------------
// out8 != 0 : write fp8 e4m3 bytes at [gm][gn] (ldc byte stride)
// vtile != 0: bf16 out tiled [n/16][m/32][(n>>3)&1][m&31][n&7] (PV A-frag tiles)
__global__ __launch_bounds__(256) void gemm_nt_k(const unsigned short* __restrict__ A,
                                                 const unsigned short* __restrict__ B,
                                                 int lda, int ldb, long sA, long sB,
                                                 const float* __restrict__ bias_m,
                                                 const float* __restrict__ bias_n,
                                                 const float* __restrict__ resid, long sR,
                                                 float* __restrict__ outF,
                                                 unsigned short* __restrict__ outB,
                                                 unsigned char* __restrict__ out8,
                                                 int ldc, long sC, int vtile){
  __shared__ unsigned short As[64][40];
  __shared__ unsigned short Bs[64][40];
  const int b  = blockIdx.z;
  const int m0 = blockIdx.x * 64, n0 = blockIdx.y * 64;
  const unsigned short* Ab = A + (size_t)b * sA;
  const unsigned short* Bb = B + (size_t)b * sB;
  const int t = threadIdx.x;
  const int lane = t & 63, w = t >> 6;
  const int g = lane >> 4, r = lane & 15;
  const int wm = (w >> 1) * 32, wn = (w & 1) * 32;
  const int lrow = t >> 2, lcol = (t & 3) * 8;
  f32x4 acc00 = {0,0,0,0}, acc01 = {0,0,0,0}, acc10 = {0,0,0,0}, acc11 = {0,0,0,0};
  for (int ks = 0; ks < 8; ++ks){
    short8 av = *(const short8*)(Ab + (size_t)(m0 + lrow) * lda + ks*32 + lcol);
    short8 bv = *(const short8*)(Bb + (size_t)(n0 + lrow) * ldb + ks*32 + lcol);
    __syncthreads();
    *(short8*)&As[lrow][lcol] = av;
    *(short8*)&Bs[lrow][lcol] = bv;
    __syncthreads();
    short8 af0 = *(const short8*)&As[wm + r][g*8];
    short8 af1 = *(const short8*)&As[wm + 16 + r][g*8];
    short8 bf0 = *(const short8*)&Bs[wn + r][g*8];
    short8 bf1 = *(const short8*)&Bs[wn + 16 + r][g*8];
    acc00 = __builtin_amdgcn_mfma_f32_16x16x32_bf16(af0, bf0, acc00, 0, 0, 0);
    acc01 = __builtin_amdgcn_mfma_f32_16x16x32_bf16(af0, bf1, acc01, 0, 0, 0);
    acc10 = __builtin_amdgcn_mfma_f32_16x16x32_bf16(af1, bf0, acc10, 0, 0, 0);
    acc11 = __builtin_amdgcn_mfma_f32_16x16x32_bf16(af1, bf1, acc11, 0, 0, 0);
  }
  f32x4 accs[2][2] = {{acc00, acc01},{acc10, acc11}};
  #pragma unroll
  for (int mi = 0; mi < 2; ++mi)
    #pragma unroll
    for (int ni = 0; ni < 2; ++ni)
      #pragma unroll
      for (int j = 0; j < 4; ++j){
        int gm = m0 + wm + mi*16 + g*4 + j;
        int gn = n0 + wn + ni*16 + r;
        float vv = accs[mi][ni][j];
        if (bias_m) vv += bias_m[gm];
        if (bias_n) vv += bias_n[gn];
        if (resid)  vv += resid[(size_t)b*sR + (size_t)gm*ldc + gn];
        if (out8){
          out8[(size_t)b*sC + (size_t)gm*ldc + gn] = (unsigned char)(cvt2_fp8(vv, vv) & 0xff);
        } else if (outB){
          size_t off;
          if (vtile)
            off = (size_t)b*sC + (size_t)(gn >> 4)*4096 + (size_t)(gm >> 5)*512
                + ((gn >> 3) & 1)*256 + (gm & 31)*8 + (gn & 7);
          else
            off = (size_t)b*sC + (size_t)gm*ldc + gn;
          outB[off] = f2bf(vv);
        } else {
          outF[(size_t)b*sC + (size_t)gm*ldc + gn] = vv;
        }
      }
}

// ---------------- flash attention: fp8 QK, 4 waves = 2qw x 2cg, 2 q-tiles/wave ----------------
// qk8[b][n][512B] fp8 (Q bytes 0..255, K 256..511); vt = bf16 PV A-frag tiles.
// Fixed-M softmax p = exp2(S*scale - 24). 2 blocks/CU, 3-barrier split-stage schedule.
__global__ __launch_bounds__(256, 2) void attn_k(const unsigned char* __restrict__ qk8,
                                                 const unsigned short* __restrict__ vt,
                                                 unsigned short* __restrict__ po,
                                                 float* __restrict__ ml){
  __shared__ __align__(16) char smem[65536];   // K 16KB | V 32KB | P 16KB
  const int id = blockIdx.x;
  const int combo = id & 15, qb = id >> 4;     // combo&7 -> XCD: K/V L2-local per combo
  const int b = combo >> 2, ks = combo & 3;
  const int q0 = qb * 128;
  const int t = threadIdx.x, lane = t & 63, w = t >> 6;
  const int qw = w & 1, cg = w >> 1;
  const int hi = lane >> 5, l31 = lane & 31;
  const unsigned char* qkb = qk8 + (size_t)b * 4096 * 512;
  const unsigned short* vtb = vt + (size_t)b * 1048576;
  char* Kb = smem;
  char* Vb = smem + 16384;
  char* Pb = smem + 49152;
  const float SQL2 = 0.0625f * 1.44269504088896340736f;

  // ---- Q fragments direct from global (fp8, 8B each) ----
  unsigned long long qf[2][16];
  #pragma unroll
  for (int qt = 0; qt < 2; ++qt){
    const unsigned char* qrow = qkb + (size_t)(q0 + qw*64 + qt*32 + l31) * 512;
    #pragma unroll
    for (int s = 0; s < 16; ++s)
      qf[qt][s] = *(const unsigned long long*)(qrow + s*16 + hi*8);
  }

  auto stageK = [&](int kt){   // 64 rows x 256B fp8, 16-row XOR swizzle
    const int kbase = ks*1024 + kt*64;
    #pragma unroll
    for (int ii = 0; ii < 4; ++ii){
      int r0 = (w*4 + ii)*4 + (lane >> 4);
      const unsigned char* src = qkb + (size_t)(kbase + r0)*512 + 256
                               + (((lane & 15)*16) ^ ((r0 & 15) << 4));
      gload16(src, Kb + (w*4 + ii)*1024);
    }
  };
  auto stageV = [&](int kt){   // 32 tiles of 1KB, identity layout (pre-tiled global)
    const int kbase = ks*1024 + kt*64;
    #pragma unroll
    for (int ii = 0; ii < 8; ++ii){
      int tix = w*8 + ii;
      const unsigned short* src = vtb + (size_t)((kbase >> 4) + (tix >> 3))*4096
                                + (tix & 7)*512 + lane*8;
      gload16(src, Vb + tix*1024);
    }
  };
  stageK(0); stageV(0);

  f32x16 O[2][4];
  #pragma unroll
  for (int qt = 0; qt < 2; ++qt)
    #pragma unroll
    for (int cb = 0; cb < 4; ++cb)
      #pragma unroll
      for (int jj = 0; jj < 16; ++jj) O[qt][cb][jj] = 0.f;
  float l0 = 0.f, l1 = 0.f;

  auto packP = [&](const f32x16& S, int qtg, float& lsum){
    float p[16];
    #pragma unroll
    for (int jj = 0; jj < 16; ++jj) p[jj] = exp2f(fmaf(S[jj], SQL2, -24.0f));
    lsum += ((p[0]+p[1]) + (p[2]+p[3])) + ((p[4]+p[5]) + (p[6]+p[7]))
          + ((p[8]+p[9]) + (p[10]+p[11])) + ((p[12]+p[13]) + (p[14]+p[15]));
    unsigned int a0 = cvtpk_bf16(p[0],p[1]),   a1 = cvtpk_bf16(p[2],p[3]);
    unsigned int a2 = cvtpk_bf16(p[4],p[5]),   a3 = cvtpk_bf16(p[6],p[7]);
    unsigned int a4 = cvtpk_bf16(p[8],p[9]),   a5 = cvtpk_bf16(p[10],p[11]);
    unsigned int a6 = cvtpk_bf16(p[12],p[13]), a7 = cvtpk_bf16(p[14],p[15]);
    asm("v_permlane32_swap_b32 %0, %1" : "+v"(a0), "+v"(a2));
    asm("v_permlane32_swap_b32 %0, %1" : "+v"(a1), "+v"(a3));
    asm("v_permlane32_swap_b32 %0, %1" : "+v"(a4), "+v"(a6));
    asm("v_permlane32_swap_b32 %0, %1" : "+v"(a5), "+v"(a7));
    i32x4 u0 = {(int)a0,(int)a1,(int)a2,(int)a3};
    i32x4 u1 = {(int)a4,(int)a5,(int)a6,(int)a7};
    *(short8*)(Pb + (qtg*4 + cg*2    )*1024 + lane*16) = __builtin_bit_cast(short8, u0);
    *(short8*)(Pb + (qtg*4 + cg*2 + 1)*1024 + lane*16) = __builtin_bit_cast(short8, u1);
  };

  for (int kt = 0; kt < 16; ++kt){
    WAITV0();      // own stages of tile kt landed
    BARRIER();     // B1: tile kt staged by all waves

    // ---- S^T = K[cg 32k] . Q : fp8 MFMA, K frag feeds both q-tiles ----
    f32x16 S0, S1;
    #pragma unroll
    for (int jj = 0; jj < 16; ++jj){ S0[jj] = 0.f; S1[jj] = 0.f; }
    const int krow = cg*32 + l31;
    const char* kp = Kb + krow*256;
    const int ksw = (krow & 15) << 4;
    __builtin_amdgcn_s_setprio(1);
    #pragma unroll
    for (int s = 0; s < 16; ++s){
      unsigned long long kf = *(const unsigned long long*)(kp + ((s*16 + hi*8) ^ ksw));
      S0 = __builtin_amdgcn_mfma_f32_32x32x16_fp8_fp8((long long)kf, (long long)qf[0][s], S0, 0, 0, 0);
      S1 = __builtin_amdgcn_mfma_f32_32x32x16_fp8_fp8((long long)kf, (long long)qf[1][s], S1, 0, 0, 0);
    }
    __builtin_amdgcn_s_setprio(0);

    packP(S0, qw*2 + 0, l0);
    packP(S1, qw*2 + 1, l1);
    WAITLGKM0();
    BARRIER();     // B2: all P visible; all K reads done
    if (kt < 15) stageK(kt + 1);   // K region free -> overlap with PV

    // ---- O += V . P^T : V frag feeds both q-tiles, P frag feeds 4 c-blocks ----
    __builtin_amdgcn_s_setprio(1);
    #pragma unroll
    for (int sg = 0; sg < 4; ++sg){
      short8 pf0 = *(const short8*)(Pb + ((qw*2+0)*4 + sg)*1024 + lane*16);
      short8 pf1 = *(const short8*)(Pb + ((qw*2+1)*4 + sg)*1024 + lane*16);
      #pragma unroll
      for (int cb = 0; cb < 4; ++cb){
        short8 vf = *(const short8*)(Vb + (sg*8 + cg*4 + cb)*1024 + lane*16);
        O[0][cb] = __builtin_amdgcn_mfma_f32_32x32x16_bf16(vf, pf0, O[0][cb], 0, 0, 0);
        O[1][cb] = __builtin_amdgcn_mfma_f32_32x32x16_bf16(vf, pf1, O[1][cb], 0, 0, 0);
      }
    }
    __builtin_amdgcn_s_setprio(0);

    BARRIER();     // B3: all V/P reads done
    if (kt < 15) stageV(kt + 1);   // V region free -> lands before next B1
  }

  // ---- epilogue: unnormalized partials + l partials ----
  float lf0 = l0 + __shfl_xor(l0, 32);
  float lf1 = l1 + __shfl_xor(l1, 32);
  unsigned short* pob = po + (size_t)combo * 1048576;   // [256 c][4096 q]
  #pragma unroll
  for (int qt = 0; qt < 2; ++qt)
    #pragma unroll
    for (int cb = 0; cb < 4; ++cb)
      #pragma unroll
      for (int jj = 0; jj < 16; ++jj){
        int c = cg*128 + cb*32 + (jj & 3) + 8*(jj >> 2) + 4*hi;
        int q = q0 + qw*64 + qt*32 + l31;
        pob[(size_t)c*4096 + q] = f2bf(O[qt][cb][jj]);
      }
  if (lane < 32){
    float* mlb = ml + (size_t)combo*8192 + cg*4096 + q0 + qw*64;
    mlb[lane]      = lf0;
    mlb[32 + lane] = lf1;
  }
}

// ---------------- merge the 4 k-chunks: out ho[b][q][c] bf16 ----------------
__global__ __launch_bounds__(256) void attn_merge_k(const unsigned short* __restrict__ po,
                                                    const float* __restrict__ ml,
                                                    unsigned short* __restrict__ ho){
  __shared__ float Of[64][261];
  const int b = blockIdx.y, q0 = blockIdx.x * 64;
  const int t = threadIdx.x, ql = t & 63, ci = t >> 6;
  const int q = q0 + ql;
  float L = 0.f;
  #pragma unroll
  for (int ksv = 0; ksv < 4; ++ksv){
    size_t base = (size_t)(b*4 + ksv)*8192;
    L += ml[base + q] + ml[base + 4096 + q];
  }
  float inv = 1.0f / L;
  float acc[64];
  #pragma unroll
  for (int i = 0; i < 64; ++i) acc[i] = 0.f;
  #pragma unroll
  for (int ksv = 0; ksv < 4; ++ksv){
    const unsigned short* pb = po + (size_t)(b*4 + ksv)*1048576 + q;
    #pragma unroll
    for (int i = 0; i < 64; ++i)
      acc[i] += bf2f(pb[(size_t)(ci + 4*i)*4096]);
  }
  #pragma unroll
  for (int i = 0; i < 64; ++i) Of[ql][ci + 4*i] = acc[i] * inv;
  __syncthreads();
  const int qr = t >> 2, sub = t & 3;
  const float* rowp = Of[qr];
  unsigned short* dst = ho + ((size_t)(b*4096 + q0 + qr))*256;
  #pragma unroll
  for (int jj = 0; jj < 8; ++jj){
    int c = sub*8 + jj*32;
    float4 v0 = *(const float4*)(rowp + c);
    float4 v1 = *(const float4*)(rowp + c + 4);
    short8 o;
    o[0] = (short)f2bf(v0.x); o[1] = (short)f2bf(v0.y);
    o[2] = (short)f2bf(v0.z); o[3] = (short)f2bf(v0.w);
    o[4] = (short)f2bf(v1.x); o[5] = (short)f2bf(v1.y);
    o[6] = (short)f2bf(v1.z); o[7] = (short)f2bf(v1.w);
    *(short8*)(dst + c) = o;
  }
}

// ---------------- launch ----------------
extern "C" void kernel_launch(void* const* d_in, const int* in_sizes, int n_in,
                              void* d_out, int out_size, void* d_ws, size_t ws_size,
                              hipStream_t stream){
  const float* x      = (const float*)d_in[0];
  const float* gamma  = (const float*)d_in[1];
  const float* beta   = (const float*)d_in[2];
  const float* qkv_w  = (const float*)d_in[3];
  const float* qkv_b  = (const float*)d_in[4];
  const float* proj_w = (const float*)d_in[5];
  const float* proj_b = (const float*)d_in[6];
  float* out = (float*)d_out;
  char* ws = (char*)d_ws;

  float2* partial        = (float2*)(ws + 0);                 // 2 KB
  float2* stats          = (float2*)(ws + 2048);              // 32 B
  float*  bias_qk        = (float*)(ws + 4096);               // 2 KB
  unsigned short* Wqk    = (unsigned short*)(ws + 8192);      // 512x256 bf16 (256 KB)
  unsigned short* Wv     = (unsigned short*)(ws + 270336);    // 256x256 (128 KB)
  unsigned short* Wp     = (unsigned short*)(ws + 401408);    // 256x256 (128 KB)
  unsigned short* xnt    = (unsigned short*)(ws + 532480);    // 4x4096x256 bf16 (8.4 MB)
  unsigned char*  qk8    = (unsigned char*)(ws + 8921088);    // 4x4096x512 fp8 (8.4 MB)
  unsigned short* vt     = (unsigned short*)(ws + 17309696);  // 4x1M bf16 tiled (8.4 MB)
  unsigned short* po     = (unsigned short*)(ws + 25698304);  // 16x256x4096 bf16 (33.6 MB)
  float*          ml     = (float*)(ws + 59252736);           // 16x2x4096 f32 (512 KB)
  unsigned short* ho     = xnt;  // xnt dead after QKV gemms -> reuse for attention output

  reduce_partial_k<<<dim3(64,4), 256, 0, stream>>>(x, partial);
  reduce_final_k<<<1, 256, 0, stream>>>(partial, stats);
  convert_w_k<<<1024, 256, 0, stream>>>(qkv_w, qkv_b, proj_w, Wqk, Wv, Wp, bias_qk);
  norm_transpose_k<<<dim3(64,4,4), 256, 0, stream>>>(x, gamma, beta, stats, xnt);
  // q,k fp8: qk8[b][n][o] = xn_t[b][n][:] . Wqk[o][:]   (M=4096, N=512)
  gemm_nt_k<<<dim3(64,8,4), 256, 0, stream>>>(xnt, Wqk, 256, 256, 4096L*256, 0,
      nullptr, bias_qk, nullptr, 0, nullptr, nullptr, qk8, 512, 4096L*512, 0);
  // v bf16 tiled: vt[b] tiles = Wv[o][:] . xn_t[b][n][:]  (M=256 c, N=4096 n)
  gemm_nt_k<<<dim3(4,64,4), 256, 0, stream>>>(Wv, xnt, 256, 256, 0, 4096L*256,
      qkv_b + 512, nullptr, nullptr, 0, nullptr, vt, nullptr, 4096, 256L*4096, 1);
  attn_k<<<dim3(512), 256, 0, stream>>>(qk8, vt, po, ml);
  attn_merge_k<<<dim3(64,4), 256, 0, stream>>>(po, ml, ho);
  // out[b][o][n] = Wp[o][:] . ho[b][n][:] + proj_b[o] + x[b][o][n]
  gemm_nt_k<<<dim3(4,64,4), 256, 0, stream>>>(Wp, ho, 256, 256, 0, 4096L*256,
      proj_b, nullptr, x, 1048576L, out, nullptr, nullptr, 4096, 1048576L, 0);
}

// Round 9
// 144.997 us; speedup vs baseline: 1.8272x; 1.2857x over previous
//
#include <hip/hip_runtime.h>

typedef __attribute__((ext_vector_type(8))) short short8;
typedef __attribute__((ext_vector_type(4))) float f32x4;
typedef __attribute__((ext_vector_type(16))) float f32x16;
typedef __attribute__((ext_vector_type(4))) int i32x4;

__device__ __forceinline__ unsigned short f2bf(float f){
  union { float f; unsigned int u; } cv; cv.f = f;
  unsigned int u = cv.u;
  u = (u + 0x7fffu + ((u >> 16) & 1u)) >> 16;
  return (unsigned short)u;
}
__device__ __forceinline__ float bf2f(unsigned short h){
  union { unsigned int u; float f; } cv; cv.u = ((unsigned int)h) << 16;
  return cv.f;
}

typedef unsigned int u32g __attribute__((address_space(1)));
typedef unsigned int u32l __attribute__((address_space(3)));
__device__ __forceinline__ void gload16(const void* g, void* l){
  __builtin_amdgcn_global_load_lds((const u32g*)g, (u32l*)l, 16, 0, 0);
}

__device__ __forceinline__ unsigned int cvtpk_bf16(float lo, float hi){
  unsigned int r;
  asm("v_cvt_pk_bf16_f32 %0, %1, %2" : "=v"(r) : "v"(lo), "v"(hi));
  return r;
}
__device__ __forceinline__ unsigned int cvt2_fp8(float a, float b){
  unsigned int r;
  asm("v_cvt_pk_fp8_f32 %0, %1, %2" : "=v"(r) : "v"(a), "v"(b));
  return r;
}

#define BARRIER() asm volatile("s_barrier" ::: "memory")
#define WAITV(N)  asm volatile("s_waitcnt vmcnt(" #N ")" ::: "memory")
#define WAITLGKM0() asm volatile("s_waitcnt lgkmcnt(0)" ::: "memory")

// ---------------- reduction: per-batch mean / rstd ----------------
__global__ __launch_bounds__(256) void reduce_partial_k(const float* __restrict__ x,
                                                        float2* __restrict__ partial){
  const int b = blockIdx.y, blk = blockIdx.x;
  const float4* xp = (const float4*)(x + (size_t)b*1048576 + (size_t)blk*16384);
  float s = 0.f, sq = 0.f;
  #pragma unroll
  for (int i = 0; i < 16; ++i){
    float4 v = xp[threadIdx.x + i*256];
    s  += v.x + v.y + v.z + v.w;
    sq += v.x*v.x + v.y*v.y + v.z*v.z + v.w*v.w;
  }
  #pragma unroll
  for (int m = 1; m < 64; m <<= 1){ s += __shfl_xor(s, m); sq += __shfl_xor(sq, m); }
  __shared__ float2 acc[4];
  if ((threadIdx.x & 63) == 0) acc[threadIdx.x >> 6] = make_float2(s, sq);
  __syncthreads();
  if (threadIdx.x == 0){
    float S = 0.f, Q = 0.f;
    for (int i = 0; i < 4; ++i){ S += acc[i].x; Q += acc[i].y; }
    partial[b*64 + blk] = make_float2(S, Q);
  }
}

__global__ __launch_bounds__(256) void reduce_final_k(const float2* __restrict__ partial,
                                                      float2* __restrict__ stats){
  const int w = threadIdx.x >> 6, lane = threadIdx.x & 63;
  float2 p = partial[w*64 + lane];
  float s = p.x, q = p.y;
  #pragma unroll
  for (int m = 1; m < 64; m <<= 1){ s += __shfl_xor(s, m); q += __shfl_xor(q, m); }
  if (lane == 0){
    const float inv = 1.0f/1048576.0f;
    float mean = s*inv;
    float var  = q*inv - mean*mean;
    stats[w] = make_float2(mean, rsqrtf(var + 1e-6f));
  }
}

// ---------------- weight conversion ----------------
__global__ __launch_bounds__(256) void convert_w_k(const float* __restrict__ qkv_w,
                                                   const float* __restrict__ qkv_b,
                                                   const float* __restrict__ proj_w,
                                                   unsigned short* __restrict__ Wqk,
                                                   unsigned short* __restrict__ Wv,
                                                   unsigned short* __restrict__ Wp,
                                                   float* __restrict__ bias_qk){
  int id = blockIdx.x * 256 + threadIdx.x;
  if (id < 131072){
    Wqk[id] = f2bf(qkv_w[id]);
    if (id < 512) bias_qk[id] = qkv_b[id];
  } else if (id < 196608){
    Wv[id - 131072] = f2bf(qkv_w[id]);
  } else {
    int j = id - 196608;
    Wp[j] = f2bf(proj_w[j]);
  }
}

// ---------------- GroupNorm + transpose ----------------
__global__ __launch_bounds__(256) void norm_transpose_k(const float* __restrict__ x,
                                                        const float* __restrict__ gamma,
                                                        const float* __restrict__ beta,
                                                        const float2* __restrict__ stats,
                                                        unsigned short* __restrict__ xnt){
  __shared__ float tile[64][65];
  const int b = blockIdx.z, n0 = blockIdx.x*64, c0 = blockIdx.y*64;
  const float2 st = stats[b];
  const int t = threadIdx.x;
  const int col = t & 63, rb = t >> 6;
  #pragma unroll
  for (int i = 0; i < 16; ++i){
    int rr = i*4 + rb;
    float xv = x[((size_t)b*256 + c0 + rr)*4096 + n0 + col];
    tile[rr][col] = (xv - st.x) * st.y * gamma[c0+rr] + beta[c0+rr];
  }
  __syncthreads();
  #pragma unroll
  for (int i = 0; i < 16; ++i){
    int nr = i*4 + rb;
    xnt[((size_t)b*4096 + n0 + nr)*256 + c0 + col] = f2bf(tile[col][nr]);
  }
}

// ---------------- NT GEMM ----------------
__global__ __launch_bounds__(256) void gemm_nt_k(const unsigned short* __restrict__ A,
                                                 const unsigned short* __restrict__ B,
                                                 int lda, int ldb, long sA, long sB,
                                                 const float* __restrict__ bias_m,
                                                 const float* __restrict__ bias_n,
                                                 const float* __restrict__ resid, long sR,
                                                 float* __restrict__ outF,
                                                 unsigned short* __restrict__ outB,
                                                 unsigned char* __restrict__ out8,
                                                 int ldc, long sC, int vtile){
  __shared__ unsigned short As[64][40];
  __shared__ unsigned short Bs[64][40];
  const int b  = blockIdx.z;
  const int m0 = blockIdx.x * 64, n0 = blockIdx.y * 64;
  const unsigned short* Ab = A + (size_t)b * sA;
  const unsigned short* Bb = B + (size_t)b * sB;
  const int t = threadIdx.x;
  const int lane = t & 63, w = t >> 6;
  const int g = lane >> 4, r = lane & 15;
  const int wm = (w >> 1) * 32, wn = (w & 1) * 32;
  const int lrow = t >> 2, lcol = (t & 3) * 8;
  f32x4 acc00 = {0,0,0,0}, acc01 = {0,0,0,0}, acc10 = {0,0,0,0}, acc11 = {0,0,0,0};
  for (int ks = 0; ks < 8; ++ks){
    short8 av = *(const short8*)(Ab + (size_t)(m0 + lrow) * lda + ks*32 + lcol);
    short8 bv = *(const short8*)(Bb + (size_t)(n0 + lrow) * ldb + ks*32 + lcol);
    __syncthreads();
    *(short8*)&As[lrow][lcol] = av;
    *(short8*)&Bs[lrow][lcol] = bv;
    __syncthreads();
    short8 af0 = *(const short8*)&As[wm + r][g*8];
    short8 af1 = *(const short8*)&As[wm + 16 + r][g*8];
    short8 bf0 = *(const short8*)&Bs[wn + r][g*8];
    short8 bf1 = *(const short8*)&Bs[wn + 16 + r][g*8];
    acc00 = __builtin_amdgcn_mfma_f32_16x16x32_bf16(af0, bf0, acc00, 0, 0, 0);
    acc01 = __builtin_amdgcn_mfma_f32_16x16x32_bf16(af0, bf1, acc01, 0, 0, 0);
    acc10 = __builtin_amdgcn_mfma_f32_16x16x32_bf16(af1, bf0, acc10, 0, 0, 0);
    acc11 = __builtin_amdgcn_mfma_f32_16x16x32_bf16(af1, bf1, acc11, 0, 0, 0);
  }
  f32x4 accs[2][2] = {{acc00, acc01},{acc10, acc11}};
  #pragma unroll
  for (int mi = 0; mi < 2; ++mi)
    #pragma unroll
    for (int ni = 0; ni < 2; ++ni)
      #pragma unroll
      for (int j = 0; j < 4; ++j){
        int gm = m0 + wm + mi*16 + g*4 + j;
        int gn = n0 + wn + ni*16 + r;
        float vv = accs[mi][ni][j];
        if (bias_m) vv += bias_m[gm];
        if (bias_n) vv += bias_n[gn];
        if (resid)  vv += resid[(size_t)b*sR + (size_t)gm*ldc + gn];
        if (out8){
          out8[(size_t)b*sC + (size_t)gm*ldc + gn] = (unsigned char)(cvt2_fp8(vv, vv) & 0xff);
        } else if (outB){
          size_t off;
          if (vtile)
            off = (size_t)b*sC + (size_t)(gn >> 4)*4096 + (size_t)(gm >> 5)*512
                + ((gn >> 3) & 1)*256 + (gm & 31)*8 + (gn & 7);
          else
            off = (size_t)b*sC + (size_t)gm*ldc + gn;
          outB[off] = f2bf(vv);
        } else {
          outF[(size_t)b*sC + (size_t)gm*ldc + gn] = vv;
        }
      }
}

// ---------------- flash attention: 8 waves = 4qw x 2cg, fp8 QK, counted-vmcnt dbuf ----------------
// qk8[b][n][512B] fp8 (Q 0..255, K 256..511); vt bf16 PV A-frag tiles.
// Fixed-M softmax p = exp2(S*scale - 24). ksplit=2. Per iter: vmcnt(4) / vmcnt(2), 2 barriers.
__global__ __launch_bounds__(512, 1) void attn_k(const unsigned char* __restrict__ qk8,
                                                 const unsigned short* __restrict__ vt,
                                                 unsigned short* __restrict__ po,
                                                 float* __restrict__ ml){
  __shared__ __align__(16) char smem[114688];  // 2 x (K 16KB | V 32KB) dbuf + P 16KB
  const int id = blockIdx.x;
  const int combo = id & 7, qb = id >> 3;      // combo -> XCD (K/V L2-resident per combo)
  const int b = combo >> 1, ks = combo & 1;
  const int q0 = qb * 128;
  const int t = threadIdx.x, lane = t & 63, w = t >> 6;
  const int qw = w >> 1, cg = w & 1;
  const int hi = lane >> 5, l31 = lane & 31;
  const unsigned char* qkb = qk8 + (size_t)b * 4096 * 512;
  const unsigned short* vtb = vt + (size_t)b * 1048576;
  char* Pb = smem + 98304;
  const float SQL2 = 0.0625f * 1.44269504088896340736f;

  // ---- Q fp8 fragments: wave owns q-rows q0 + qw*32 + l31 (B-operand) ----
  unsigned long long qf[16];
  {
    const unsigned char* qrow = qkb + (size_t)(q0 + qw*32 + l31) * 512;
    #pragma unroll
    for (int s = 0; s < 16; ++s) qf[s] = *(const unsigned long long*)(qrow + s*16 + hi*8);
  }

  // stage K tile (64 rows x 256B fp8): 2 loads/thread. XOR-swizzled source, linear dest.
  auto stageK = [&](int kt, char* buf){
    const int kbase = ks*2048 + kt*64;
    #pragma unroll
    for (int i2 = 0; i2 < 2; ++i2){
      int ci = w*128 + i2*64 + lane;
      int r = ci >> 4;
      const unsigned char* src = qkb + (size_t)(kbase + r)*512 + 256
                               + (((ci & 15) ^ (r & 15)) * 16);
      gload16(src, buf + w*2048 + i2*1024);
    }
  };
  // stage V (32 tiles of 1KB, identity layout from pre-tiled global): 4 loads/thread
  auto stageV = [&](int kt, char* buf){
    const int kbase = ks*2048 + kt*64;
    #pragma unroll
    for (int i = 0; i < 4; ++i){
      int tix = w*4 + i;
      const unsigned short* src = vtb + (size_t)((kbase >> 4) + (tix >> 3))*4096
                                + (tix & 7)*512 + lane*8;
      gload16(src, buf + 16384 + tix*1024);
    }
  };
  stageK(0, smem);   // 2 loads in flight
  stageV(0, smem);   // +4 = 6

  f32x16 O[4];
  #pragma unroll
  for (int cb = 0; cb < 4; ++cb)
    #pragma unroll
    for (int jj = 0; jj < 16; ++jj) O[cb][jj] = 0.f;
  float lrun = 0.f;
  const int ksw = (l31 & 15) << 4;

  for (int kt = 0; kt < 32; ++kt){
    char* cur = smem + (kt & 1)*49152;
    char* nxt = smem + ((kt + 1) & 1)*49152;

    WAITV(4);     // my K(t) landed; V(t)'s 4 stay counted
    BARRIER();    // all waves' K(t) visible; prev buffer fully consumed

    // ---- S^T = K[cg 32k] . Q : 16 fp8 MFMA, 2 chains ----
    f32x16 Sa, Sb;
    #pragma unroll
    for (int jj = 0; jj < 16; ++jj){ Sa[jj] = 0.f; Sb[jj] = 0.f; }
    const char* kp = cur + (cg*32 + l31)*256;
    __builtin_amdgcn_s_setprio(1);
    #pragma unroll
    for (int s = 0; s < 8; ++s){
      unsigned long long k0 = *(const unsigned long long*)(kp + (((2*s  )*16 + hi*8) ^ ksw));
      unsigned long long k1 = *(const unsigned long long*)(kp + (((2*s+1)*16 + hi*8) ^ ksw));
      Sa = __builtin_amdgcn_mfma_f32_32x32x16_fp8_fp8((long long)k0, (long long)qf[2*s  ], Sa, 0, 0, 0);
      Sb = __builtin_amdgcn_mfma_f32_32x32x16_fp8_fp8((long long)k1, (long long)qf[2*s+1], Sb, 0, 0, 0);
    }
    __builtin_amdgcn_s_setprio(0);

    int ktn = (kt < 31) ? kt + 1 : 31;
    stageK(ktn, nxt);   // K region of nxt free since top barrier; covered by SM+PV

    // ---- fixed-M softmax + pack ----
    float p[16];
    #pragma unroll
    for (int jj = 0; jj < 16; ++jj) p[jj] = exp2f(fmaf(Sa[jj] + Sb[jj], SQL2, -24.0f));
    lrun += ((p[0]+p[1]) + (p[2]+p[3])) + ((p[4]+p[5]) + (p[6]+p[7]))
          + ((p[8]+p[9]) + (p[10]+p[11])) + ((p[12]+p[13]) + (p[14]+p[15]));
    unsigned int a0 = cvtpk_bf16(p[0],p[1]),   a1 = cvtpk_bf16(p[2],p[3]);
    unsigned int a2 = cvtpk_bf16(p[4],p[5]),   a3 = cvtpk_bf16(p[6],p[7]);
    unsigned int a4 = cvtpk_bf16(p[8],p[9]),   a5 = cvtpk_bf16(p[10],p[11]);
    unsigned int a6 = cvtpk_bf16(p[12],p[13]), a7 = cvtpk_bf16(p[14],p[15]);
    asm("v_permlane32_swap_b32 %0, %1" : "+v"(a0), "+v"(a2));
    asm("v_permlane32_swap_b32 %0, %1" : "+v"(a1), "+v"(a3));
    asm("v_permlane32_swap_b32 %0, %1" : "+v"(a4), "+v"(a6));
    asm("v_permlane32_swap_b32 %0, %1" : "+v"(a5), "+v"(a7));
    i32x4 u0 = {(int)a0,(int)a1,(int)a2,(int)a3};
    i32x4 u1 = {(int)a4,(int)a5,(int)a6,(int)a7};
    short8 pa0 = __builtin_bit_cast(short8, u0);   // k-slice cg*2
    short8 pa1 = __builtin_bit_cast(short8, u1);   // k-slice cg*2+1
    *(short8*)(Pb + (qw*4 + cg*2    )*1024 + lane*16) = pa0;
    *(short8*)(Pb + (qw*4 + cg*2 + 1)*1024 + lane*16) = pa1;

    WAITV(2);       // my V(t) landed (K(t+1)'s 2 stay in flight)
    WAITLGKM0();    // my P writes done
    BARRIER();      // all P + all V(t) visible

    stageV(ktn, nxt);  // V region of nxt free; covered by PV + next QK

    // ---- read partner P, O += V . P^T : 4 k-slices x 4 c-blocks ----
    short8 qb0 = *(const short8*)(Pb + (qw*4 + (1-cg)*2    )*1024 + lane*16);
    short8 qb1 = *(const short8*)(Pb + (qw*4 + (1-cg)*2 + 1)*1024 + lane*16);
    short8 pf0 = cg ? qb0 : pa0;
    short8 pf1 = cg ? qb1 : pa1;
    short8 pf2 = cg ? pa0 : qb0;
    short8 pf3 = cg ? pa1 : qb1;
    const char* Vt = cur + 16384;
    __builtin_amdgcn_s_setprio(1);
    #pragma unroll
    for (int cb = 0; cb < 4; ++cb){
      short8 v0 = *(const short8*)(Vt + (0*8 + cg*4 + cb)*1024 + lane*16);
      O[cb] = __builtin_amdgcn_mfma_f32_32x32x16_bf16(v0, pf0, O[cb], 0, 0, 0);
      short8 v1 = *(const short8*)(Vt + (1*8 + cg*4 + cb)*1024 + lane*16);
      O[cb] = __builtin_amdgcn_mfma_f32_32x32x16_bf16(v1, pf1, O[cb], 0, 0, 0);
      short8 v2 = *(const short8*)(Vt + (2*8 + cg*4 + cb)*1024 + lane*16);
      O[cb] = __builtin_amdgcn_mfma_f32_32x32x16_bf16(v2, pf2, O[cb], 0, 0, 0);
      short8 v3 = *(const short8*)(Vt + (3*8 + cg*4 + cb)*1024 + lane*16);
      O[cb] = __builtin_amdgcn_mfma_f32_32x32x16_bf16(v3, pf3, O[cb], 0, 0, 0);
    }
    __builtin_amdgcn_s_setprio(0);
  }
  WAITV(0);   // drain tail stages before endpgm

  // ---- epilogue: unnormalized partials + l partials ----
  float lf = lrun + __shfl_xor(lrun, 32);
  const int qg = q0 + qw*32 + l31;
  unsigned short* pob = po + (size_t)combo * 1048576;   // [256 c][4096 q]
  #pragma unroll
  for (int cb = 0; cb < 4; ++cb)
    #pragma unroll
    for (int jj = 0; jj < 16; ++jj){
      int c = cg*128 + cb*32 + (jj & 3) + 8*(jj >> 2) + 4*hi;
      pob[(size_t)c*4096 + qg] = f2bf(O[cb][jj]);
    }
  if (lane < 32)
    ml[(size_t)(combo*2 + cg)*4096 + qg] = lf;
}

// ---------------- merge the 2 k-chunks: out ho[b][q][c] bf16 ----------------
__global__ __launch_bounds__(256) void attn_merge_k(const unsigned short* __restrict__ po,
                                                    const float* __restrict__ ml,
                                                    unsigned short* __restrict__ ho){
  __shared__ float Of[64][261];
  const int b = blockIdx.y, q0 = blockIdx.x * 64;
  const int t = threadIdx.x, ql = t & 63, ci = t >> 6;
  const int q = q0 + ql;
  float L = ml[(size_t)((b*2+0)*2 + 0)*4096 + q] + ml[(size_t)((b*2+0)*2 + 1)*4096 + q]
          + ml[(size_t)((b*2+1)*2 + 0)*4096 + q] + ml[(size_t)((b*2+1)*2 + 1)*4096 + q];
  float inv = 1.0f / L;
  const unsigned short* p0 = po + (size_t)(b*2+0)*1048576 + q;
  const unsigned short* p1 = po + (size_t)(b*2+1)*1048576 + q;
  #pragma unroll
  for (int i = 0; i < 64; ++i){
    int c = ci + 4*i;
    float v = bf2f(p0[(size_t)c*4096]) + bf2f(p1[(size_t)c*4096]);
    Of[ql][c] = v * inv;
  }
  __syncthreads();
  const int qr = t >> 2, sub = t & 3;
  const float* rowp = Of[qr];
  unsigned short* dst = ho + ((size_t)(b*4096 + q0 + qr))*256;
  #pragma unroll
  for (int jj = 0; jj < 8; ++jj){
    int c = sub*8 + jj*32;
    float4 v0 = *(const float4*)(rowp + c);
    float4 v1 = *(const float4*)(rowp + c + 4);
    short8 o;
    o[0] = (short)f2bf(v0.x); o[1] = (short)f2bf(v0.y);
    o[2] = (short)f2bf(v0.z); o[3] = (short)f2bf(v0.w);
    o[4] = (short)f2bf(v1.x); o[5] = (short)f2bf(v1.y);
    o[6] = (short)f2bf(v1.z); o[7] = (short)f2bf(v1.w);
    *(short8*)(dst + c) = o;
  }
}

// ---------------- launch ----------------
extern "C" void kernel_launch(void* const* d_in, const int* in_sizes, int n_in,
                              void* d_out, int out_size, void* d_ws, size_t ws_size,
                              hipStream_t stream){
  const float* x      = (const float*)d_in[0];
  const float* gamma  = (const float*)d_in[1];
  const float* beta   = (const float*)d_in[2];
  const float* qkv_w  = (const float*)d_in[3];
  const float* qkv_b  = (const float*)d_in[4];
  const float* proj_w = (const float*)d_in[5];
  const float* proj_b = (const float*)d_in[6];
  float* out = (float*)d_out;
  char* ws = (char*)d_ws;

  float2* partial        = (float2*)(ws + 0);
  float2* stats          = (float2*)(ws + 2048);
  float*  bias_qk        = (float*)(ws + 4096);
  unsigned short* Wqk    = (unsigned short*)(ws + 8192);      // 512x256 bf16
  unsigned short* Wv     = (unsigned short*)(ws + 270336);    // 256x256
  unsigned short* Wp     = (unsigned short*)(ws + 401408);    // 256x256
  unsigned short* xnt    = (unsigned short*)(ws + 532480);    // 4x4096x256 bf16 (8.4 MB)
  unsigned char*  qk8    = (unsigned char*)(ws + 8921088);    // 4x4096x512 fp8 (8.4 MB)
  unsigned short* vt     = (unsigned short*)(ws + 17309696);  // 4x1M bf16 tiled (8.4 MB)
  unsigned short* po     = (unsigned short*)(ws + 25698304);  // 8x256x4096 bf16 (16.8 MB)
  float*          ml     = (float*)(ws + 42475520);           // 8x2x4096 f32 (256 KB)
  unsigned short* ho     = xnt;  // xnt dead after QKV gemms -> reuse

  reduce_partial_k<<<dim3(64,4), 256, 0, stream>>>(x, partial);
  reduce_final_k<<<1, 256, 0, stream>>>(partial, stats);
  convert_w_k<<<1024, 256, 0, stream>>>(qkv_w, qkv_b, proj_w, Wqk, Wv, Wp, bias_qk);
  norm_transpose_k<<<dim3(64,4,4), 256, 0, stream>>>(x, gamma, beta, stats, xnt);
  // q,k fp8: qk8[b][n][o]
  gemm_nt_k<<<dim3(64,8,4), 256, 0, stream>>>(xnt, Wqk, 256, 256, 4096L*256, 0,
      nullptr, bias_qk, nullptr, 0, nullptr, nullptr, qk8, 512, 4096L*512, 0);
  // v bf16 tiled
  gemm_nt_k<<<dim3(4,64,4), 256, 0, stream>>>(Wv, xnt, 256, 256, 0, 4096L*256,
      qkv_b + 512, nullptr, nullptr, 0, nullptr, vt, nullptr, 4096, 256L*4096, 1);
  attn_k<<<dim3(256), 512, 0, stream>>>(qk8, vt, po, ml);
  attn_merge_k<<<dim3(64,4), 256, 0, stream>>>(po, ml, ho);
  // out = proj(ho) + x
  gemm_nt_k<<<dim3(4,64,4), 256, 0, stream>>>(Wp, ho, 256, 256, 0, 4096L*256,
      proj_b, nullptr, x, 1048576L, out, nullptr, nullptr, 4096, 1048576L, 0);
}